// Round 15
// baseline (159.664 us; speedup 1.0000x reference)
//
#include <hip/hip_runtime.h>

// ---------------------------------------------------------------------------
// ConvFeatureExtractor: profile = rownorm( freq @ softmax(matches/T, axis=1)^T )
//   matches[f,i] = Thi[f, i>>6] + Tlo[f, i&63]  (separable!), F=8192, M=4096,
//   B=1024, K=6.  =>  probs[f,i] = e1[f,i>>6] * e2[f,i&63],  Z = (sum e1)(sum e2).
// R21: remove scheduling fences from R20 (70.8us). Two never-isolated items:
//   (1) s_setprio toggles between k-halves -- m190 measured setprio NEGATIVE
//       on pre-8-phase GEMM structures; cargo-culted since R7. Removed.
//   (2) cross-half ILP: load all 16 a-frags up front and present the 16
//       MFMA-chains + e1-folds as one flat region so fold(h=0) overlaps
//       MFMA(h=1). VGPR ~95 (a-frags +32), still 4 blocks/CU (<=128, pinned).
//   Everything else = R19/R20 best: BK=128, 32 iters, 2x16KB ping-pong,
//   1 vmcnt(0)+barrier/iter, XOR swizzle, f32 e1 fold, XCD remap.
//   Ledger: R7/8/14/16/17/18/20 null, R11/12/13/15 regress, R9+R19 wins.
// ---------------------------------------------------------------------------

typedef __bf16  bf16x8 __attribute__((ext_vector_type(8)));
typedef float   f32x4  __attribute__((ext_vector_type(4)));

#define GLD16(gp, lp)                                                          \
  __builtin_amdgcn_global_load_lds(                                            \
      (const __attribute__((address_space(1))) void*)(gp),                     \
      (__attribute__((address_space(3))) void*)(lp), 16, 0, 0)

__device__ __forceinline__ short f2bf(float x) {
  unsigned u = __float_as_uint(x);
  unsigned r = (u + 0x7fffu + ((u >> 16) & 1u)) >> 16;   // RNE
  return (short)r;
}

__device__ __forceinline__ float wave_max(float v) {
  #pragma unroll
  for (int off = 32; off; off >>= 1) v = fmaxf(v, __shfl_xor(v, off, 64));
  return v;
}
__device__ __forceinline__ float wave_sum(float v) {
  #pragma unroll
  for (int off = 32; off; off >>= 1) v += __shfl_xor(v, off, 64);
  return v;
}

// ---------------- k1: prep = cast (blocks 0..4095) + tables (4096..6143) ----
__global__ __launch_bounds__(256) void prep_kernel(const float* __restrict__ freq,
                                                   short* __restrict__ freqb,
                                                   const float* __restrict__ kp,
                                                   const float* __restrict__ temp,
                                                   float* __restrict__ E1t,
                                                   float* __restrict__ E2) {
  if (blockIdx.x < 4096) {
    int idx = blockIdx.x * 256 + threadIdx.x;
    float4 v = ((const float4*)freq)[idx];
    short4 o;
    o.x = f2bf(v.x); o.y = f2bf(v.y); o.z = f2bf(v.z); o.w = f2bf(v.w);
    ((short4*)freqb)[idx] = o;
  } else {
    const int t = threadIdx.x;
    const int lane = t & 63, wave = t >> 6;
    const int f = (blockIdx.x - 4096) * 4 + wave;
    const float* P = kp + f * 24;
    const int d0 = (lane >> 4) & 3, d1 = (lane >> 2) & 3, d2 = lane & 3;
    const float thi = P[d0 * 6 + 0] + P[d1 * 6 + 1] + P[d2 * 6 + 2];
    const float tlo = P[d0 * 6 + 3] + P[d1 * 6 + 4] + P[d2 * 6 + 5];
    const float mxhi = wave_max(thi), mxlo = wave_max(tlo);
    const float invT = 1.0f / temp[0];
    const float e1 = __expf((thi - mxhi) * invT);
    const float e2 = __expf((tlo - mxlo) * invT);
    const float s1 = wave_sum(e1), s2 = wave_sum(e2);
    const float invZ = 1.0f / (s1 * s2);
    E1t[lane * 8192 + f] = e1 * invZ;
    E2[(size_t)f * 64 + lane] = e2;
  }
}

// ---------------- k2: GEMM pooled = A(1024x4096) * B^T, B[f,i]=e1[f,i>>6]e2[f,i&63]
// TM=64, TN=128, BK=128 (2 x 64-halves); 32 iterations; grid 1024 (4/CU),
// 4 waves 1Mx4N (wave 64x32). Ping-pong 2x16KB A buffers. 1 vmcnt(0)+barrier
// per iteration. No setprio; flat 16-chain MFMA/fold region for cross-half ILP.
__global__ __launch_bounds__(256, 4) void gemm_kernel(const short* __restrict__ A,
                                                      const float* __restrict__ E1t,
                                                      const float* __restrict__ E2,
                                                      float* __restrict__ C) {
  __shared__ short As[2][2][64 * 64];            // [buf][half][row*64]

  const int t = threadIdx.x;
  const int lane = t & 63, wave = t >> 6;
  const int quad = lane >> 4, l16 = lane & 15;

  // XCD remap: d -> XCD k = d%8 owns L in [128k,128k+128) = m-strips {2k,2k+1}.
  const int d  = blockIdx.y * 64 + blockIdx.x;
  const int L  = (d & 7) * 128 + (d >> 3);
  const int m0 = (L >> 6) * 64;                  // batch tile (16 strips)
  const int n0 = (L & 63) * 128;                 // filter tile (64 strips)
  const int wn = wave * 32;                      // wave's n-offset

  f32x4 acc[4][2];
  #pragma unroll
  for (int i = 0; i < 4; i++)
    #pragma unroll
    for (int j = 0; j < 2; j++) acc[i][j] = (f32x4){0.f, 0.f, 0.f, 0.f};

  // constant bf16 e2 fragments: lane (l16,quad) of frag (ks,j) covers
  // k = (ks*4+quad)*8 + 0..7 for filter row nrow[j]
  int nrow[2];
  #pragma unroll
  for (int j = 0; j < 2; j++) nrow[j] = n0 + wn + j * 16 + l16;
  bf16x8 e2f[2][2];
  #pragma unroll
  for (int j = 0; j < 2; j++)
    #pragma unroll
    for (int ks = 0; ks < 2; ks++) {
      const float* p = E2 + (size_t)nrow[j] * 64 + (ks * 4 + quad) * 8;
      float4 lo = *(const float4*)p, hi = *(const float4*)(p + 4);
      bf16x8 bb;
      bb[0] = (__bf16)lo.x; bb[1] = (__bf16)lo.y;
      bb[2] = (__bf16)lo.z; bb[3] = (__bf16)lo.w;
      bb[4] = (__bf16)hi.x; bb[5] = (__bf16)hi.y;
      bb[6] = (__bf16)hi.z; bb[7] = (__bf16)hi.w;
      e2f[ks][j] = bb;
    }

  const int lane_row = lane >> 3;                      // 0..7 within 8-row chunk
  const int src_col = ((lane & 7) ^ lane_row) * 8;     // swizzled col within half
  const int sw = l16 & 7;                              // reader swizzle key (= row&7)
  const int chunk = wave * 2;                          // wave stages chunks 2w, 2w+1
  const short* Abase = A + (size_t)(m0 + lane_row) * 4096 + src_col;

  // hoisted lane-constant LDS read offsets (shorts)
  const int rc0 = l16 * 64 + ((quad ^ sw) * 8);        // ks=0
  const int rc1 = l16 * 64 + (((quad + 4) ^ sw) * 8);  // ks=1

  #define STG(it, buf) do {                                                    \
    _Pragma("unroll")                                                          \
    for (int c = 0; c < 2; c++)                                                \
      _Pragma("unroll")                                                        \
      for (int h = 0; h < 2; h++)                                              \
        GLD16(Abase + (size_t)((chunk + c) * 8) * 4096 + (it) * 128 + h * 64,  \
              &As[buf][h][(chunk + c) * 512 + lane * 8]);                      \
  } while (0)

  // prologue: stage it=0, e1(it=0) for both halves
  STG(0, 0);
  float e1n[2][2], e1c[2][2];                    // [half][j]
  #pragma unroll
  for (int h = 0; h < 2; h++)
    #pragma unroll
    for (int j = 0; j < 2; j++) e1n[h][j] = E1t[h * 8192 + nrow[j]];

  const f32x4 Z4 = (f32x4){0.f, 0.f, 0.f, 0.f};

  #pragma unroll 1
  for (int it = 0; it < 32; ++it) {
    const int cb = it & 1;
    const int tn = (it + 1 > 31) ? 31 : it + 1;        // tail: dummy restage

    // S(it) + e1(it) issued a full iteration ago -> cheap full drain.
    asm volatile("s_waitcnt vmcnt(0)" ::: "memory");
    __builtin_amdgcn_s_barrier();                      // publish tile it

    STG(tn, cb ^ 1);                                   // next tile, full phase of flight
    #pragma unroll
    for (int h = 0; h < 2; h++)
      #pragma unroll
      for (int j = 0; j < 2; j++) e1c[h][j] = e1n[h][j];
    #pragma unroll
    for (int h = 0; h < 2; h++)
      #pragma unroll
      for (int j = 0; j < 2; j++) e1n[h][j] = E1t[(2 * tn + h) * 8192 + nrow[j]];

    const short* b0 = &As[cb][0][rc0];
    const short* b1 = &As[cb][0][rc1];

    // load ALL 16 a-frags (both halves), then one flat MFMA/fold region:
    // scheduler can overlap fold(h=0) with MFMA ramp of h=1. No setprio.
    bf16x8 a[2][4][2];
    #pragma unroll
    for (int h = 0; h < 2; h++)
      #pragma unroll
      for (int i = 0; i < 4; i++) {
        a[h][i][0] = *(const bf16x8*)(b0 + h * 4096 + i * 1024);
        a[h][i][1] = *(const bf16x8*)(b1 + h * 4096 + i * 1024);
      }

    #pragma unroll
    for (int h = 0; h < 2; h++)
      #pragma unroll
      for (int j = 0; j < 2; j++) {
        const float s = e1c[h][j];
        const f32x4 s4 = (f32x4){s, s, s, s};
        #pragma unroll
        for (int i = 0; i < 4; i++) {
          f32x4 P = __builtin_amdgcn_mfma_f32_16x16x32_bf16(a[h][i][0], e2f[0][j], Z4, 0, 0, 0);
          P = __builtin_amdgcn_mfma_f32_16x16x32_bf16(a[h][i][1], e2f[1][j], P, 0, 0, 0);
          acc[i][j] += s4 * P;                         // f32 fold of e1
        }
      }
    // no bottom barrier: restage target cb^1 was read at it-1; those reads
    // completed before this iteration's top barrier.
  }

  asm volatile("s_waitcnt vmcnt(0)" ::: "memory");     // drain tail dummies

  // epilogue: C/D layout col=lane&15, row=quad*4+reg
  #pragma unroll
  for (int i = 0; i < 4; i++) {
    #pragma unroll
    for (int r = 0; r < 4; r++) {
      const int brow = m0 + i * 16 + quad * 4 + r;
      float* crow = C + (size_t)brow * 8192 + n0 + wn + l16;
      #pragma unroll
      for (int j = 0; j < 2; j++) crow[j * 16] = acc[i][j][r];
    }
  }
  #undef STG
}

// ---------------- k3: row-normalize d_out (1024 rows of 8192) ----------------
__global__ __launch_bounds__(256) void norm_kernel(float* __restrict__ out) {
  const int b = blockIdx.x;
  const int t = threadIdx.x;
  const int lane = t & 63, wave = t >> 6;
  __shared__ float red[4];

  float4* row = (float4*)(out + (size_t)b * 8192);   // 2048 float4
  float4 v[8];
  float s = 0.0f;
  #pragma unroll
  for (int q = 0; q < 8; q++) {
    v[q] = row[q * 256 + t];
    s += (v[q].x + v[q].y) + (v[q].z + v[q].w);
  }
  float ws = wave_sum(s);
  if (lane == 0) red[wave] = ws;
  __syncthreads();
  float tot = (red[0] + red[1]) + (red[2] + red[3]);
  float inv = 1.0f / tot;
  #pragma unroll
  for (int q = 0; q < 8; q++) {
    v[q].x *= inv; v[q].y *= inv; v[q].z *= inv; v[q].w *= inv;
    row[q * 256 + t] = v[q];
  }
}

// ---------------------------------------------------------------------------
extern "C" void kernel_launch(void* const* d_in, const int* in_sizes, int n_in,
                              void* d_out, int out_size, void* d_ws, size_t ws_size,
                              hipStream_t stream) {
  const float* freq    = (const float*)d_in[0];   // 1024*4096
  const float* kparams = (const float*)d_in[1];   // 8192*4*6
  const float* temp    = (const float*)d_in[2];   // 1
  // d_in[3] = kmer_idcs (recomputed analytically in-kernel)

  float* out = (float*)d_out;                     // 1024*8192 f32

  short* freqb = (short*)d_ws;                    // 1024*4096 bf16 = 8 MiB
  float* E1t   = (float*)(freqb + (size_t)1024 * 4096);  // 64*8192 f32 = 2 MiB
  float* E2    = E1t + (size_t)64 * 8192;                // 8192*64 f32 = 2 MiB

  prep_kernel<<<6144, 256, 0, stream>>>(freq, freqb, kparams, temp, E1t, E2);
  gemm_kernel<<<dim3(64, 16), 256, 0, stream>>>(freqb, E1t, E2, out);
  norm_kernel<<<1024, 256, 0, stream>>>(out);
}

// Round 16
// 156.493 us; speedup vs baseline: 1.0203x; 1.0203x over previous
//
#include <hip/hip_runtime.h>

// ---------------------------------------------------------------------------
// ConvFeatureExtractor: profile = rownorm( freq @ softmax(matches/T, axis=1)^T )
//   matches[f,i] = Thi[f, i>>6] + Tlo[f, i&63]  (separable!), F=8192, M=4096,
//   B=1024, K=6.  =>  probs[f,i] = e1[f,i>>6] * e2[f,i&63],  Z = (sum e1)(sum e2).
// R22: amortize the per-iteration convoy over 2x work (the R19 mechanism,
//   N-axis notch). TN 128->256 at BK=128: 32 iters unchanged, convoy cost
//   per FLOP halves; A re-reads halve (FETCH ~12MB); e1 traffic halves.
//   Grid 32x16 = 512 = 2 blocks/CU -- safe: R17 measured runtime invariant
//   across 2/4/8 blocks/CU. Wave tile 64x64 (1Mx4N), acc 64 VGPR, ~160 tot
//   -> 2 waves/SIMD (launch_bounds(256,2)). All else = R20 verbatim:
//   2x16KB-per-half ping-pong, 1 vmcnt(0)+barrier/iter, XOR swizzle, hoisted
//   LDS offsets, per-half setprio (R21 proved removing it regresses), f32 e1
//   fold, XCD remap (1MB A slice/XCD). Ledger: R7/8/14/16/17/18/20 null,
//   R11/12/13/15/21 regress, R9 (dataflow) + R19 (sync amortize) wins.
// ---------------------------------------------------------------------------

typedef __bf16  bf16x8 __attribute__((ext_vector_type(8)));
typedef float   f32x4  __attribute__((ext_vector_type(4)));

#define GLD16(gp, lp)                                                          \
  __builtin_amdgcn_global_load_lds(                                            \
      (const __attribute__((address_space(1))) void*)(gp),                     \
      (__attribute__((address_space(3))) void*)(lp), 16, 0, 0)

__device__ __forceinline__ short f2bf(float x) {
  unsigned u = __float_as_uint(x);
  unsigned r = (u + 0x7fffu + ((u >> 16) & 1u)) >> 16;   // RNE
  return (short)r;
}

__device__ __forceinline__ float wave_max(float v) {
  #pragma unroll
  for (int off = 32; off; off >>= 1) v = fmaxf(v, __shfl_xor(v, off, 64));
  return v;
}
__device__ __forceinline__ float wave_sum(float v) {
  #pragma unroll
  for (int off = 32; off; off >>= 1) v += __shfl_xor(v, off, 64);
  return v;
}

// ---------------- k1: prep = cast (blocks 0..4095) + tables (4096..6143) ----
__global__ __launch_bounds__(256) void prep_kernel(const float* __restrict__ freq,
                                                   short* __restrict__ freqb,
                                                   const float* __restrict__ kp,
                                                   const float* __restrict__ temp,
                                                   float* __restrict__ E1t,
                                                   float* __restrict__ E2) {
  if (blockIdx.x < 4096) {
    int idx = blockIdx.x * 256 + threadIdx.x;
    float4 v = ((const float4*)freq)[idx];
    short4 o;
    o.x = f2bf(v.x); o.y = f2bf(v.y); o.z = f2bf(v.z); o.w = f2bf(v.w);
    ((short4*)freqb)[idx] = o;
  } else {
    const int t = threadIdx.x;
    const int lane = t & 63, wave = t >> 6;
    const int f = (blockIdx.x - 4096) * 4 + wave;
    const float* P = kp + f * 24;
    const int d0 = (lane >> 4) & 3, d1 = (lane >> 2) & 3, d2 = lane & 3;
    const float thi = P[d0 * 6 + 0] + P[d1 * 6 + 1] + P[d2 * 6 + 2];
    const float tlo = P[d0 * 6 + 3] + P[d1 * 6 + 4] + P[d2 * 6 + 5];
    const float mxhi = wave_max(thi), mxlo = wave_max(tlo);
    const float invT = 1.0f / temp[0];
    const float e1 = __expf((thi - mxhi) * invT);
    const float e2 = __expf((tlo - mxlo) * invT);
    const float s1 = wave_sum(e1), s2 = wave_sum(e2);
    const float invZ = 1.0f / (s1 * s2);
    E1t[lane * 8192 + f] = e1 * invZ;
    E2[(size_t)f * 64 + lane] = e2;
  }
}

// ---------------- k2: GEMM pooled = A(1024x4096) * B^T, B[f,i]=e1[f,i>>6]e2[f,i&63]
// TM=64, TN=256, BK=128 (2 x 64-halves); 32 iterations; grid 32x16 = 512
// blocks (2/CU), 4 waves 1Mx4N (wave 64x64 = 4x4 frags). Ping-pong 2x16KB
// A buffers. 1 vmcnt(0)+barrier per iteration. Per-half setprio.
__global__ __launch_bounds__(256, 2) void gemm_kernel(const short* __restrict__ A,
                                                      const float* __restrict__ E1t,
                                                      const float* __restrict__ E2,
                                                      float* __restrict__ C) {
  __shared__ short As[2][2][64 * 64];            // [buf][half][row*64]

  const int t = threadIdx.x;
  const int lane = t & 63, wave = t >> 6;
  const int quad = lane >> 4, l16 = lane & 15;

  // XCD remap: d -> XCD k = d%8 owns L in [64k,64k+64) = m-strips {2k,2k+1}
  // = A rows [128k,128k+128) (1MB slice, L2-pinned); n varies fastest.
  const int d  = blockIdx.y * 32 + blockIdx.x;
  const int L  = (d & 7) * 64 + (d >> 3);
  const int m0 = (L >> 5) * 64;                  // batch tile (16 strips)
  const int n0 = (L & 31) * 256;                 // filter tile (32 strips)
  const int wn = wave * 64;                      // wave's n-offset

  f32x4 acc[4][4];
  #pragma unroll
  for (int i = 0; i < 4; i++)
    #pragma unroll
    for (int j = 0; j < 4; j++) acc[i][j] = (f32x4){0.f, 0.f, 0.f, 0.f};

  // constant bf16 e2 fragments: lane (l16,quad) of frag (ks,j) covers
  // k = (ks*4+quad)*8 + 0..7 for filter row nrow[j]
  int nrow[4];
  #pragma unroll
  for (int j = 0; j < 4; j++) nrow[j] = n0 + wn + j * 16 + l16;
  bf16x8 e2f[2][4];
  #pragma unroll
  for (int j = 0; j < 4; j++)
    #pragma unroll
    for (int ks = 0; ks < 2; ks++) {
      const float* p = E2 + (size_t)nrow[j] * 64 + (ks * 4 + quad) * 8;
      float4 lo = *(const float4*)p, hi = *(const float4*)(p + 4);
      bf16x8 bb;
      bb[0] = (__bf16)lo.x; bb[1] = (__bf16)lo.y;
      bb[2] = (__bf16)lo.z; bb[3] = (__bf16)lo.w;
      bb[4] = (__bf16)hi.x; bb[5] = (__bf16)hi.y;
      bb[6] = (__bf16)hi.z; bb[7] = (__bf16)hi.w;
      e2f[ks][j] = bb;
    }

  const int lane_row = lane >> 3;                      // 0..7 within 8-row chunk
  const int src_col = ((lane & 7) ^ lane_row) * 8;     // swizzled col within half
  const int sw = l16 & 7;                              // reader swizzle key (= row&7)
  const int chunk = wave * 2;                          // wave stages chunks 2w, 2w+1
  const short* Abase = A + (size_t)(m0 + lane_row) * 4096 + src_col;

  // hoisted lane-constant LDS read offsets (shorts)
  const int rc0 = l16 * 64 + ((quad ^ sw) * 8);        // ks=0
  const int rc1 = l16 * 64 + (((quad + 4) ^ sw) * 8);  // ks=1

  #define STG(it, buf) do {                                                    \
    _Pragma("unroll")                                                          \
    for (int c = 0; c < 2; c++)                                                \
      _Pragma("unroll")                                                        \
      for (int h = 0; h < 2; h++)                                              \
        GLD16(Abase + (size_t)((chunk + c) * 8) * 4096 + (it) * 128 + h * 64,  \
              &As[buf][h][(chunk + c) * 512 + lane * 8]);                      \
  } while (0)

  // prologue: stage it=0, e1(it=0) for both halves
  STG(0, 0);
  float e1n[2][4], e1c[2][4];                    // [half][j]
  #pragma unroll
  for (int h = 0; h < 2; h++)
    #pragma unroll
    for (int j = 0; j < 4; j++) e1n[h][j] = E1t[h * 8192 + nrow[j]];

  const f32x4 Z4 = (f32x4){0.f, 0.f, 0.f, 0.f};

  #pragma unroll 1
  for (int it = 0; it < 32; ++it) {
    const int cb = it & 1;
    const int tn = (it + 1 > 31) ? 31 : it + 1;        // tail: dummy restage

    // S(it) + e1(it) issued a full iteration ago -> cheap full drain.
    asm volatile("s_waitcnt vmcnt(0)" ::: "memory");
    __builtin_amdgcn_s_barrier();                      // publish tile it

    STG(tn, cb ^ 1);                                   // next tile, full phase of flight
    #pragma unroll
    for (int h = 0; h < 2; h++)
      #pragma unroll
      for (int j = 0; j < 4; j++) e1c[h][j] = e1n[h][j];
    #pragma unroll
    for (int h = 0; h < 2; h++)
      #pragma unroll
      for (int j = 0; j < 4; j++) e1n[h][j] = E1t[(2 * tn + h) * 8192 + nrow[j]];

    const short* b0 = &As[cb][0][rc0];
    const short* b1 = &As[cb][0][rc1];

    #pragma unroll
    for (int h = 0; h < 2; h++) {                      // two 64-wide k-halves
      bf16x8 a[4][2];
      #pragma unroll
      for (int i = 0; i < 4; i++) {
        a[i][0] = *(const bf16x8*)(b0 + h * 4096 + i * 1024);
        a[i][1] = *(const bf16x8*)(b1 + h * 4096 + i * 1024);
      }
      __builtin_amdgcn_s_setprio(1);
      #pragma unroll
      for (int j = 0; j < 4; j++) {
        const float s = e1c[h][j];
        const f32x4 s4 = (f32x4){s, s, s, s};
        #pragma unroll
        for (int i = 0; i < 4; i++) {
          f32x4 P = __builtin_amdgcn_mfma_f32_16x16x32_bf16(a[i][0], e2f[0][j], Z4, 0, 0, 0);
          P = __builtin_amdgcn_mfma_f32_16x16x32_bf16(a[i][1], e2f[1][j], P, 0, 0, 0);
          acc[i][j] += s4 * P;                         // f32 fold of e1
        }
      }
      __builtin_amdgcn_s_setprio(0);
    }
    // no bottom barrier: restage target cb^1 was read at it-1; those reads
    // completed before this iteration's top barrier.
  }

  asm volatile("s_waitcnt vmcnt(0)" ::: "memory");     // drain tail dummies

  // epilogue: C/D layout col=lane&15, row=quad*4+reg
  #pragma unroll
  for (int i = 0; i < 4; i++) {
    #pragma unroll
    for (int r = 0; r < 4; r++) {
      const int brow = m0 + i * 16 + quad * 4 + r;
      float* crow = C + (size_t)brow * 8192 + n0 + wn + l16;
      #pragma unroll
      for (int j = 0; j < 4; j++) crow[j * 16] = acc[i][j][r];
    }
  }
  #undef STG
}

// ---------------- k3: row-normalize d_out (1024 rows of 8192) ----------------
__global__ __launch_bounds__(256) void norm_kernel(float* __restrict__ out) {
  const int b = blockIdx.x;
  const int t = threadIdx.x;
  const int lane = t & 63, wave = t >> 6;
  __shared__ float red[4];

  float4* row = (float4*)(out + (size_t)b * 8192);   // 2048 float4
  float4 v[8];
  float s = 0.0f;
  #pragma unroll
  for (int q = 0; q < 8; q++) {
    v[q] = row[q * 256 + t];
    s += (v[q].x + v[q].y) + (v[q].z + v[q].w);
  }
  float ws = wave_sum(s);
  if (lane == 0) red[wave] = ws;
  __syncthreads();
  float tot = (red[0] + red[1]) + (red[2] + red[3]);
  float inv = 1.0f / tot;
  #pragma unroll
  for (int q = 0; q < 8; q++) {
    v[q].x *= inv; v[q].y *= inv; v[q].z *= inv; v[q].w *= inv;
    row[q * 256 + t] = v[q];
  }
}

// ---------------------------------------------------------------------------
extern "C" void kernel_launch(void* const* d_in, const int* in_sizes, int n_in,
                              void* d_out, int out_size, void* d_ws, size_t ws_size,
                              hipStream_t stream) {
  const float* freq    = (const float*)d_in[0];   // 1024*4096
  const float* kparams = (const float*)d_in[1];   // 8192*4*6
  const float* temp    = (const float*)d_in[2];   // 1
  // d_in[3] = kmer_idcs (recomputed analytically in-kernel)

  float* out = (float*)d_out;                     // 1024*8192 f32

  short* freqb = (short*)d_ws;                    // 1024*4096 bf16 = 8 MiB
  float* E1t   = (float*)(freqb + (size_t)1024 * 4096);  // 64*8192 f32 = 2 MiB
  float* E2    = E1t + (size_t)64 * 8192;                // 8192*64 f32 = 2 MiB

  prep_kernel<<<6144, 256, 0, stream>>>(freq, freqb, kparams, temp, E1t, E2);
  gemm_kernel<<<dim3(32, 16), 256, 0, stream>>>(freqb, E1t, E2, out);
  norm_kernel<<<1024, 256, 0, stream>>>(out);
}